// Round 8
// baseline (137.245 us; speedup 1.0000x reference)
//
#include <hip/hip_runtime.h>
#include <cmath>

namespace {

typedef _Float16 half8 __attribute__((ext_vector_type(8)));
typedef _Float16 half4v __attribute__((ext_vector_type(4)));
typedef float f32x4 __attribute__((ext_vector_type(4)));

constexpr int M_TOTAL = 32 * 1024;   // B*T
constexpr int K_CH    = 512;
constexpr int NV      = 640;         // G*V
constexpr int D_CV    = 128;
constexpr int NSLOT   = 10;          // 640/64

constexpr int BM = 128, BN = 64, BK = 32;
constexpr int NTILE  = NV / BN;        // 10
constexpr int NPANEL = M_TOTAL / BM;   // 256
constexpr int NBLK   = NTILE * NPANEL; // 2560 (divisible by 8)
constexpr int KT     = K_CH / BK;      // 16

constexpr int LBUF = 12288;            // f16 elems / buffer (24 KB)
// buffer layout (f16 elems): Ah 0 | Al 4096 | Bh 8192 | Bl 10240

constexpr float LO_SCALE = 4096.0f;    // keep lo-plane f16-normal
constexpr float LO_INV   = 1.0f / 4096.0f;

__device__ __forceinline__ void gld16(const void* g, void* l) {
  __builtin_amdgcn_global_load_lds(
      (__attribute__((address_space(1))) void*)g,
      (__attribute__((address_space(3))) void*)l, 16, 0, 0);
}

// ---------- prep: W[512][640] f32 -> Wth/Wtl [640][512] f16 (k-major) -------
__global__ __launch_bounds__(256)
void prep_w(const float* __restrict__ W, _Float16* __restrict__ Wth,
            _Float16* __restrict__ Wtl)
{
  __shared__ float tile[32][33];
  const int bk = blockIdx.x & 15;
  const int bn = blockIdx.x >> 4;
  const int k0 = bk * 32, n0 = bn * 32;
  const int t = threadIdx.x;
  const int nn = t & 31, kk = t >> 5;
  #pragma unroll
  for (int p = 0; p < 4; ++p)
    tile[kk + p * 8][nn] = W[(size_t)(k0 + kk + p * 8) * NV + n0 + nn];
  __syncthreads();
  const int kx = t & 31, nx = t >> 5;
  #pragma unroll
  for (int p = 0; p < 4; ++p) {
    const float v = tile[kx][nx + p * 8];
    const _Float16 h = (_Float16)v;
    const _Float16 l = (_Float16)((v - (float)h) * LO_SCALE);
    const size_t o = (size_t)(n0 + nx + p * 8) * K_CH + k0 + kx;
    Wth[o] = h;
    Wtl[o] = l;
  }
}

// ---------- prep: x f32 -> Xh/Xl f16 planes (row-major [32768][512]) --------
__global__ __launch_bounds__(256)
void prep_x(const float* __restrict__ x, _Float16* __restrict__ Xh,
            _Float16* __restrict__ Xl)
{
  const size_t i = ((size_t)blockIdx.x * 256 + threadIdx.x) * 2;
  #pragma unroll
  for (int j = 0; j < 2; ++j) {
    const float4 v = reinterpret_cast<const float4*>(x)[i + j];
    const float* pv = &v.x;
    half4v h, l;
    #pragma unroll
    for (int e = 0; e < 4; ++e) {
      const _Float16 hh = (_Float16)pv[e];
      h[e] = hh;
      l[e] = (_Float16)((pv[e] - (float)hh) * LO_SCALE);
    }
    reinterpret_cast<half4v*>(Xh)[i + j] = h;
    reinterpret_cast<half4v*>(Xl)[i + j] = l;
  }
}

// ---------- main: 32x64/wave split-f16 MFMA GEMM, 3 blocks/CU ---------------
__global__ __launch_bounds__(256, 3)
void gvq_mfma6(const _Float16* __restrict__ Xh, const _Float16* __restrict__ Xl,
               const _Float16* __restrict__ Wth, const _Float16* __restrict__ Wtl,
               const float* __restrict__ bias, const float* __restrict__ u,
               float* __restrict__ pval, int* __restrict__ pidx)
{
  __shared__ __align__(16) _Float16 lds[2 * LBUF];   // 48 KB

  const int chunk = NBLK / 8;
  const int nid   = (blockIdx.x % 8) * chunk + blockIdx.x / 8;
  const int panel = nid / NTILE, ntile = nid % NTILE;
  const int m0 = panel * BM, n0 = ntile * BN;

  const int t    = threadIdx.x;
  const int wv   = t >> 6, lane = t & 63;
  const int li   = lane & 15, q = lane >> 4;

  // staging: chunk c -> row c>>2, slot c&3; slot holds global chunk
  // (c&3) ^ ((c>>3)&3)  (both-sides swizzle, rule #21).
  const int r0 = t >> 2;
  const int gc = (t & 3) ^ ((t >> 3) & 3);
  const _Float16* pxh = Xh  + (size_t)(m0 + r0) * K_CH + gc * 8;
  const _Float16* pxl = Xl  + (size_t)(m0 + r0) * K_CH + gc * 8;
  const _Float16* pbh = Wth + (size_t)(n0 + r0) * K_CH + gc * 8;
  const _Float16* pbl = Wtl + (size_t)(n0 + r0) * K_CH + gc * 8;

  f32x4 acc1[2][4];   // hi*hi
  f32x4 acc2[2][4];   // hi*lo' + lo'*hi  (lo scaled by 4096)
  #pragma unroll
  for (int i = 0; i < 2; ++i)
    #pragma unroll
    for (int j = 0; j < 4; ++j) {
      acc1[i][j] = (f32x4){0.f, 0.f, 0.f, 0.f};
      acc2[i][j] = (f32x4){0.f, 0.f, 0.f, 0.f};
    }

  auto stage = [&](int kt, int b) {   // 6 gld16 per thread
    const int ko = kt * BK;
    _Float16* L = &lds[b * LBUF];
    gld16(pxh + ko,                      L + 0     + wv * 512);
    gld16(pxh + (size_t)64 * K_CH + ko,  L + 2048  + wv * 512);
    gld16(pxl + ko,                      L + 4096  + wv * 512);
    gld16(pxl + (size_t)64 * K_CH + ko,  L + 6144  + wv * 512);
    gld16(pbh + ko,                      L + 8192  + wv * 512);
    gld16(pbl + ko,                      L + 10240 + wv * 512);
  };

  // frag-read swizzle slot: row = base + li, (row>>1)&3 == (li>>1)&3
  const int soff = ((q ^ ((li >> 1) & 3)) << 3);   // elems within row
  const int arow = (wv * 32 + li) * 32;            // + fm*512
  const int brow = li * 32;                        // + fn*512

  stage(0, 0);
  asm volatile("s_waitcnt vmcnt(0)" ::: "memory");
  __builtin_amdgcn_s_barrier();
  __builtin_amdgcn_sched_barrier(0);

  #pragma unroll
  for (int kt = 0; kt < KT; ++kt) {
    const int cur = kt & 1;
    if (kt + 1 < KT) stage(kt + 1, cur ^ 1);   // issue first; fly under compute

    const _Float16* L = &lds[cur * LBUF];
    half8 bh[4], bl[4], ah[2], al[2];
    #pragma unroll
    for (int fn = 0; fn < 4; ++fn) {
      bh[fn] = *reinterpret_cast<const half8*>(L + 8192  + brow + fn * 512 + soff);
      bl[fn] = *reinterpret_cast<const half8*>(L + 10240 + brow + fn * 512 + soff);
    }
    #pragma unroll
    for (int fm = 0; fm < 2; ++fm) {
      ah[fm] = *reinterpret_cast<const half8*>(L + arow + fm * 512 + soff);
      al[fm] = *reinterpret_cast<const half8*>(L + 4096 + arow + fm * 512 + soff);
    }
    __builtin_amdgcn_s_setprio(1);
    #pragma unroll
    for (int fm = 0; fm < 2; ++fm)
      #pragma unroll
      for (int fn = 0; fn < 4; ++fn) {
        acc1[fm][fn] = __builtin_amdgcn_mfma_f32_16x16x32_f16(
            ah[fm], bh[fn], acc1[fm][fn], 0, 0, 0);
        acc2[fm][fn] = __builtin_amdgcn_mfma_f32_16x16x32_f16(
            ah[fm], bl[fn], acc2[fm][fn], 0, 0, 0);
        acc2[fm][fn] = __builtin_amdgcn_mfma_f32_16x16x32_f16(
            al[fm], bh[fn], acc2[fm][fn], 0, 0, 0);
      }
    __builtin_amdgcn_s_setprio(0);

    if (kt + 1 < KT) {
      // stage(kt+1) landed + all waves' reads of buf[cur] done (MFMA data-dep)
      asm volatile("s_waitcnt vmcnt(0)" ::: "memory");
      __builtin_amdgcn_s_barrier();
      __builtin_amdgcn_sched_barrier(0);   // keep next iter's ds_reads below
    }
  }

  // ---- epilogue: bias + gumbel (fast log), argmax per 64-col slot ----
  const int colbase = n0 + li;
  float bb[4];
  #pragma unroll
  for (int fn = 0; fn < 4; ++fn) bb[fn] = bias[colbase + fn * 16];

  const int slot = ntile;
  #pragma unroll
  for (int fm = 0; fm < 2; ++fm) {
    #pragma unroll
    for (int r = 0; r < 4; ++r) {
      const int m = m0 + wv * 32 + fm * 16 + q * 4 + r;
      float bv = -INFINITY;
      int   bi = 0x7fffffff;
      #pragma unroll
      for (int fn = 0; fn < 4; ++fn) {
        const float uu  = u[(size_t)m * NV + colbase + fn * 16];
        const float g   = -__logf(-__logf(uu));
        const float val = acc1[fm][fn][r] + acc2[fm][fn][r] * LO_INV
                          + bb[fn] + g;
        const int   n   = colbase + fn * 16;
        if (val > bv) { bv = val; bi = n; }   // fn ascending => first max kept
      }
      #pragma unroll
      for (int s = 1; s <= 8; s <<= 1) {      // reduce over 16 li-lanes
        const float ov = __shfl_xor(bv, s);
        const int   oi = __shfl_xor(bi, s);
        if (ov > bv || (ov == bv && oi < bi)) { bv = ov; bi = oi; }
      }
      if (li == 0) {
        pval[(size_t)m * NSLOT + slot] = bv;
        pidx[(size_t)m * NSLOT + slot] = bi;
      }
    }
  }
}

// ---------- reduce 5 partials per (m,g), gather codevector ----------
__global__ __launch_bounds__(256)
void gvq_gather(const float* __restrict__ pval,
                const int*   __restrict__ pidx,
                const float* __restrict__ cv,
                float* __restrict__ out)
{
  const int tid  = threadIdx.x;
  const int w    = tid >> 6;
  const int lane = tid & 63;
  const int m    = blockIdx.x * 4 + w;
  const int g    = lane >> 5;

  const float* pv = &pval[(size_t)m * NSLOT + g * 5];
  const int*   pi = &pidx[(size_t)m * NSLOT + g * 5];
  float bv = pv[0];
  int   bi = pi[0];
  #pragma unroll
  for (int s = 1; s < 5; ++s) {
    const float v = pv[s];
    const int   i = pi[s];
    if (v > bv || (v == bv && i < bi)) { bv = v; bi = i; }
  }
  const float4 src = *reinterpret_cast<const float4*>(
      &cv[(size_t)bi * D_CV + (lane & 31) * 4]);
  *reinterpret_cast<float4*>(&out[(size_t)m * 256 + lane * 4]) = src;
}

}  // namespace

extern "C" void kernel_launch(void* const* d_in, const int* in_sizes, int n_in,
                              void* d_out, int out_size, void* d_ws, size_t ws_size,
                              hipStream_t stream)
{
  const float* x    = (const float*)d_in[0];
  const float* W    = (const float*)d_in[1];
  const float* bias = (const float*)d_in[2];
  const float* cv   = (const float*)d_in[3];
  const float* u    = (const float*)d_in[4];
  float* out = (float*)d_out;

  _Float16* Wth  = (_Float16*)d_ws;
  _Float16* Wtl  = Wth + (size_t)NV * K_CH;
  float*    pval = (float*)(Wtl + (size_t)NV * K_CH);
  int*      pidx = (int*)(pval + (size_t)M_TOTAL * NSLOT);
  _Float16* Xh   = (_Float16*)(pidx + (size_t)M_TOTAL * NSLOT);
  _Float16* Xl   = Xh + (size_t)M_TOTAL * K_CH;

  hipLaunchKernelGGL(prep_w, dim3(320), dim3(256), 0, stream, W, Wth, Wtl);
  hipLaunchKernelGGL(prep_x, dim3(8192), dim3(256), 0, stream, x, Xh, Xl);
  hipLaunchKernelGGL(gvq_mfma6, dim3(NBLK), dim3(256), 0, stream,
                     Xh, Xl, Wth, Wtl, bias, u, pval, pidx);
  hipLaunchKernelGGL(gvq_gather, dim3(M_TOTAL / 4), dim3(256), 0, stream,
                     pval, pidx, cv, out);
}